// Round 1
// baseline (2035.183 us; speedup 1.0000x reference)
//
#include <hip/hip_runtime.h>
#include <hip/hip_fp16.h>

typedef unsigned int u32;
typedef _Float16 half2v __attribute__((ext_vector_type(2)));
typedef _Float16 half4v __attribute__((ext_vector_type(4)));
typedef _Float16 half8v __attribute__((ext_vector_type(8)));
typedef float f32x4 __attribute__((ext_vector_type(4)));

#define T_DIM 1024
#define B_DIM 256
#define H_DIM 256
#define G_DIM 768   // 3*H

// ---------------------------------------------------------------------------
// prep: transpose + f32->f16 for both weight matrices.
// WiT/WhT[g][k] = W[k][g]  (g in [0,768), k in [0,256))
// ---------------------------------------------------------------------------
__global__ void prep_kernel(const float* __restrict__ Wi,
                            const float* __restrict__ Wh,
                            _Float16* __restrict__ WiT,
                            _Float16* __restrict__ WhT) {
  int idx = blockIdx.x * 256 + threadIdx.x;
  const int total = G_DIM * H_DIM;
  const float* src = Wi;
  _Float16* dst = WiT;
  if (idx >= total) { idx -= total; src = Wh; dst = WhT; }
  int g = idx >> 8;     // 0..767
  int k = idx & 255;    // 0..255
  dst[idx] = (_Float16)src[(size_t)k * G_DIM + g];
}

// ---------------------------------------------------------------------------
// Phase 1: gi[M][768] (f16) = ins[M][256] (f32) @ Wi + bi, via MFMA f16.
// 128x128 tile, BK=64, 4 waves (2x2), 16x16x32 MFMA. XCD-swizzled block ids
// so the 6 N-tiles sharing an A-tile land on one XCD (A read from HBM once).
// ---------------------------------------------------------------------------
#define BM 128
#define BN 128
#define BK 64
#define LDK 72   // padded f16 leading dim (144B rows -> ~2-way LDS banks)

__global__ __launch_bounds__(256, 2) void gemm_gi_kernel(
    const float* __restrict__ A,       // ins [M][256]
    const _Float16* __restrict__ BT,   // WiT [768][256]
    const float* __restrict__ bias,    // bi [768] f32
    _Float16* __restrict__ C)          // gi [M][768]
{
  __shared__ _Float16 As[BM * LDK];
  __shared__ _Float16 Bs[BN * LDK];

  const int tid  = threadIdx.x;
  const int lane = tid & 63;
  const int wid  = tid >> 6;
  const int wr   = wid >> 1;   // 0..1
  const int wc   = wid & 1;    // 0..1

  // bijective swizzle: 12288 blocks, 8 XCDs, 6 N-tiles per A-tile
  const int id   = blockIdx.x;
  const int xcd  = id & 7;
  const int slot = id >> 3;          // 0..1535 per XCD
  const int nt   = slot % 6;
  const int mt   = (slot / 6) * 8 + xcd;  // 0..2047
  const int m0 = mt * BM;
  const int n0 = nt * BN;

  f32x4 acc[4][4] = {};

  for (int kt = 0; kt < H_DIM; kt += BK) {
    // stage A tile (convert f32->f16 inline), 128 rows x 64 k
#pragma unroll
    for (int i = 0; i < 8; ++i) {
      int c   = tid + i * 256;       // 0..2047
      int row = c >> 4;              // 0..127
      int kc  = (c & 15) << 2;       // 0..60
      const float4 v = *(const float4*)(A + (size_t)(m0 + row) * H_DIM + kt + kc);
      half4v h;
      h.x = (_Float16)v.x; h.y = (_Float16)v.y;
      h.z = (_Float16)v.z; h.w = (_Float16)v.w;
      *(half4v*)(&As[row * LDK + kc]) = h;
    }
    // stage B tile from WiT (already f16, k-contiguous rows)
#pragma unroll
    for (int i = 0; i < 8; ++i) {
      int c   = tid + i * 256;
      int row = c >> 4;
      int kc  = (c & 15) << 2;
      half4v v = *(const half4v*)(BT + (size_t)(n0 + row) * H_DIM + kt + kc);
      *(half4v*)(&Bs[row * LDK + kc]) = v;
    }
    __syncthreads();

#pragma unroll
    for (int kk = 0; kk < 2; ++kk) {
      half8v af[4], bf[4];
#pragma unroll
      for (int m = 0; m < 4; ++m)
        af[m] = *(const half8v*)(&As[(wr*64 + m*16 + (lane & 15)) * LDK + kk*32 + (lane >> 4)*8]);
#pragma unroll
      for (int n = 0; n < 4; ++n)
        bf[n] = *(const half8v*)(&Bs[(wc*64 + n*16 + (lane & 15)) * LDK + kk*32 + (lane >> 4)*8]);
#pragma unroll
      for (int m = 0; m < 4; ++m)
#pragma unroll
        for (int n = 0; n < 4; ++n)
          acc[m][n] = __builtin_amdgcn_mfma_f32_16x16x32_f16(af[m], bf[n], acc[m][n], 0, 0, 0);
    }
    __syncthreads();
  }

  // epilogue: +bias, f32->f16, scalar 2B stores
#pragma unroll
  for (int n = 0; n < 4; ++n) {
    const int col = n0 + wc*64 + n*16 + (lane & 15);
    const float bv = bias[col];
#pragma unroll
    for (int m = 0; m < 4; ++m) {
#pragma unroll
      for (int q = 0; q < 4; ++q) {
        const int row = m0 + wr*64 + m*16 + (lane >> 4)*4 + q;
        C[(size_t)row * G_DIM + col] = (_Float16)(acc[m][n][q] + bv);
      }
    }
  }
}

// ---------------------------------------------------------------------------
// Phase 2: persistent GRU scan. 256 wgs (1 per chain/CU) x 768 threads.
// Thread j holds column j of WhT in 128 packed-f16 VGPRs for the whole kernel.
// Per step: h (f16, 512B) broadcast via LDS; 128 v_dot2_f32_f16 per thread;
// r/z/n exchange via LDS; 2 barriers.
// ---------------------------------------------------------------------------
__device__ __forceinline__ float dot2f(u32 a, u32 b, float c) {
#if __has_builtin(__builtin_amdgcn_fdot2)
  return __builtin_amdgcn_fdot2(__builtin_bit_cast(half2v, a),
                                __builtin_bit_cast(half2v, b), c, false);
#else
  half2v av = __builtin_bit_cast(half2v, a);
  half2v bv = __builtin_bit_cast(half2v, b);
  return c + (float)av.x * (float)bv.x + (float)av.y * (float)bv.y;
#endif
}

__device__ __forceinline__ float sigmoidf_fast(float x) {
  return __builtin_amdgcn_rcpf(1.f + __expf(-x));
}
__device__ __forceinline__ float tanhf_fast(float x) {
  return 1.f - 2.f * __builtin_amdgcn_rcpf(__expf(2.f * x) + 1.f);
}

__global__ __launch_bounds__(G_DIM, 3) void gru_scan_kernel(
    const _Float16* __restrict__ WhT,   // [768][256]
    const _Float16* __restrict__ gi,    // [T][B][768]
    const int* __restrict__ resets,     // [T][B] (int32 flags)
    const float* __restrict__ h0,       // [B][256]
    const float* __restrict__ bhn,      // [256]
    float* __restrict__ ys)             // [T][B][256]
{
  const int b = blockIdx.x;
  const int j = threadIdx.x;            // 0..767

  __shared__ __align__(16) _Float16 h_lds[H_DIM];
  __shared__ float ex[G_DIM];
  __shared__ float exn[H_DIM];

  // persistent weights: column j of WhT, 256 f16 = 128 dwords in VGPRs
  u32 w[128];
  {
    const uint4* wp = (const uint4*)(WhT + (size_t)j * H_DIM);
#pragma unroll
    for (int i = 0; i < 32; ++i) {
      uint4 v = wp[i];
      w[4*i+0] = v.x; w[4*i+1] = v.y; w[4*i+2] = v.z; w[4*i+3] = v.w;
    }
  }

  const float bn = (j >= 2*H_DIM) ? bhn[j - 2*H_DIM] : 0.f;

  float hprev = 0.f;
  {
    const int r0 = resets[b];           // resets[0][b]
    if (j < H_DIM) {
      hprev = r0 ? 0.f : h0[(size_t)b * H_DIM + j];
      h_lds[j] = (_Float16)hprev;
    }
  }
  __syncthreads();

  const _Float16* gptr = gi + (size_t)b * G_DIM + j;

  for (int t = 0; t < T_DIM; ++t) {
    // issued early; consumed after the dot loop (latency hidden)
    const float gij = (float)gptr[(size_t)t * (B_DIM * G_DIM)];
    const int rstn  = (t + 1 < T_DIM) ? resets[(t + 1) * B_DIM + b] : 0;

    float acc = 0.f;
    const uint4* hb = (const uint4*)h_lds;
#pragma unroll
    for (int i = 0; i < 32; ++i) {
      uint4 hv = hb[i];                       // broadcast ds_read_b128
      acc = dot2f(w[4*i+0], hv.x, acc);
      acc = dot2f(w[4*i+1], hv.y, acc);
      acc = dot2f(w[4*i+2], hv.z, acc);
      acc = dot2f(w[4*i+3], hv.w, acc);
    }

    if (j < 2*H_DIM) {
      ex[j] = acc + gij;                      // r,z preactivations
    } else {
      ex[j] = acc + bn;                       // hn + bhn
      exn[j - 2*H_DIM] = gij;                 // pass gi_n through
    }
    __syncthreads();

    if (j < H_DIM) {
      const float r = sigmoidf_fast(ex[j]);
      const float z = sigmoidf_fast(ex[j + H_DIM]);
      const float n = tanhf_fast(exn[j] + r * ex[j + 2*H_DIM]);
      const float hn = (1.f - z) * n + z * hprev;
      ys[(size_t)t * (B_DIM * H_DIM) + (size_t)b * H_DIM + j] = hn;
      hprev = rstn ? 0.f : hn;                // next step's reset applied to carry
      h_lds[j] = (_Float16)hprev;
    }
    __syncthreads();
  }
}

// sentinel: distinctive failure signature if workspace is too small
__global__ void sentinel_kernel(float* out, int n) {
  int i = blockIdx.x * 256 + threadIdx.x;
  if (i < n) out[i] = 12345.0f;
}

// ---------------------------------------------------------------------------
extern "C" void kernel_launch(void* const* d_in, const int* in_sizes, int n_in,
                              void* d_out, int out_size, void* d_ws, size_t ws_size,
                              hipStream_t stream) {
  const float* ins    = (const float*)d_in[0];
  const int*   resets = (const int*)d_in[1];
  const float* h0     = (const float*)d_in[2];
  const float* Wi     = (const float*)d_in[3];
  const float* bi     = (const float*)d_in[4];
  const float* Wh     = (const float*)d_in[5];
  const float* bhn    = (const float*)d_in[6];
  float* ys = (float*)d_out;

  const size_t wbytes  = (size_t)G_DIM * H_DIM * 2;            // 393,216
  const size_t gibytes = (size_t)T_DIM * B_DIM * G_DIM * 2;    // 402,653,184
  const size_t need = 2 * wbytes + gibytes;
  if (ws_size < need) {
    sentinel_kernel<<<(out_size + 255) / 256, 256, 0, stream>>>(ys, out_size);
    return;
  }

  char* ws = (char*)d_ws;
  _Float16* WiT = (_Float16*)ws;
  _Float16* WhT = (_Float16*)(ws + wbytes);
  _Float16* gi  = (_Float16*)(ws + 2 * wbytes);

  prep_kernel<<<(2 * G_DIM * H_DIM) / 256, 256, 0, stream>>>(Wi, Wh, WiT, WhT);

  const int M = T_DIM * B_DIM;                 // 262144
  const int nblocks = (M / BM) * (G_DIM / BN); // 2048*6 = 12288
  gemm_gi_kernel<<<nblocks, 256, 0, stream>>>(ins, WiT, bi, gi);

  gru_scan_kernel<<<B_DIM, G_DIM, 0, stream>>>(WhT, gi, resets, h0, bhn, ys);
}

// Round 3
// 1637.208 us; speedup vs baseline: 1.2431x; 1.2431x over previous
//
#include <hip/hip_runtime.h>
#include <hip/hip_fp16.h>

typedef unsigned int u32;
typedef _Float16 half2v __attribute__((ext_vector_type(2)));
typedef _Float16 half4v __attribute__((ext_vector_type(4)));
typedef _Float16 half8v __attribute__((ext_vector_type(8)));
typedef float f32x4 __attribute__((ext_vector_type(4)));

#define T_DIM 1024
#define B_DIM 256
#define H_DIM 256
#define G_DIM 768   // 3*H

// ---------------------------------------------------------------------------
// prep: transpose + f32->f16 for both weight matrices.
// WiT/WhT[g][k] = W[k][g]  (g in [0,768), k in [0,256))
// ---------------------------------------------------------------------------
__global__ void prep_kernel(const float* __restrict__ Wi,
                            const float* __restrict__ Wh,
                            _Float16* __restrict__ WiT,
                            _Float16* __restrict__ WhT) {
  int idx = blockIdx.x * 256 + threadIdx.x;
  const int total = G_DIM * H_DIM;
  const float* src = Wi;
  _Float16* dst = WiT;
  if (idx >= total) { idx -= total; src = Wh; dst = WhT; }
  int g = idx >> 8;     // 0..767
  int k = idx & 255;    // 0..255
  dst[idx] = (_Float16)src[(size_t)k * G_DIM + g];
}

// ---------------------------------------------------------------------------
// Phase 1: gi[M][768] (f16) = ins[M][256] (f32) @ Wi + bi, via MFMA f16.
// (unchanged; ~350us including prep, secondary target)
// ---------------------------------------------------------------------------
#define BM 128
#define BN 128
#define BK 64
#define LDK 72   // padded f16 leading dim

__global__ __launch_bounds__(256, 2) void gemm_gi_kernel(
    const float* __restrict__ A,       // ins [M][256]
    const _Float16* __restrict__ BT,   // WiT [768][256]
    const float* __restrict__ bias,    // bi [768] f32
    _Float16* __restrict__ C)          // gi [M][768]
{
  __shared__ _Float16 As[BM * LDK];
  __shared__ _Float16 Bs[BN * LDK];

  const int tid  = threadIdx.x;
  const int lane = tid & 63;
  const int wid  = tid >> 6;
  const int wr   = wid >> 1;
  const int wc   = wid & 1;

  const int id   = blockIdx.x;
  const int xcd  = id & 7;
  const int slot = id >> 3;
  const int nt   = slot % 6;
  const int mt   = (slot / 6) * 8 + xcd;
  const int m0 = mt * BM;
  const int n0 = nt * BN;

  f32x4 acc[4][4] = {};

  for (int kt = 0; kt < H_DIM; kt += BK) {
#pragma unroll
    for (int i = 0; i < 8; ++i) {
      int c   = tid + i * 256;
      int row = c >> 4;
      int kc  = (c & 15) << 2;
      const float4 v = *(const float4*)(A + (size_t)(m0 + row) * H_DIM + kt + kc);
      half4v h;
      h.x = (_Float16)v.x; h.y = (_Float16)v.y;
      h.z = (_Float16)v.z; h.w = (_Float16)v.w;
      *(half4v*)(&As[row * LDK + kc]) = h;
    }
#pragma unroll
    for (int i = 0; i < 8; ++i) {
      int c   = tid + i * 256;
      int row = c >> 4;
      int kc  = (c & 15) << 2;
      half4v v = *(const half4v*)(BT + (size_t)(n0 + row) * H_DIM + kt + kc);
      *(half4v*)(&Bs[row * LDK + kc]) = v;
    }
    __syncthreads();

#pragma unroll
    for (int kk = 0; kk < 2; ++kk) {
      half8v af[4], bf[4];
#pragma unroll
      for (int m = 0; m < 4; ++m)
        af[m] = *(const half8v*)(&As[(wr*64 + m*16 + (lane & 15)) * LDK + kk*32 + (lane >> 4)*8]);
#pragma unroll
      for (int n = 0; n < 4; ++n)
        bf[n] = *(const half8v*)(&Bs[(wc*64 + n*16 + (lane & 15)) * LDK + kk*32 + (lane >> 4)*8]);
#pragma unroll
      for (int m = 0; m < 4; ++m)
#pragma unroll
        for (int n = 0; n < 4; ++n)
          acc[m][n] = __builtin_amdgcn_mfma_f32_16x16x32_f16(af[m], bf[n], acc[m][n], 0, 0, 0);
    }
    __syncthreads();
  }

#pragma unroll
  for (int n = 0; n < 4; ++n) {
    const int col = n0 + wc*64 + n*16 + (lane & 15);
    const float bv = bias[col];
#pragma unroll
    for (int m = 0; m < 4; ++m) {
#pragma unroll
      for (int q = 0; q < 4; ++q) {
        const int row = m0 + wr*64 + m*16 + (lane >> 4)*4 + q;
        C[(size_t)row * G_DIM + col] = (_Float16)(acc[m][n][q] + bv);
      }
    }
  }
}

// ---------------------------------------------------------------------------
// Phase 2: persistent GRU scan. 256 wgs x 512 threads. Thread pair (2j,2j+1)
// owns output index j: each holds Wh columns (r_j,z_j,n_j) over HALF of k.
// Per step: h broadcast from LDS, 192 dot2 in 3 independent chains,
// shfl_xor(1) combine, redundant activation, double-buffered h, ONE barrier.
// FIX vs round 2: the carry written to hbuf is the RESET-MASKED hnext
// (reference applies reset to the next step's carry before h@Wh).
// ---------------------------------------------------------------------------
__device__ __forceinline__ float dot2f(u32 a, u32 b, float c) {
#if __has_builtin(__builtin_amdgcn_fdot2)
  return __builtin_amdgcn_fdot2(__builtin_bit_cast(half2v, a),
                                __builtin_bit_cast(half2v, b), c, false);
#else
  half2v av = __builtin_bit_cast(half2v, a);
  half2v bv = __builtin_bit_cast(half2v, b);
  return c + (float)av.x * (float)bv.x + (float)av.y * (float)bv.y;
#endif
}

__device__ __forceinline__ float sigmoidf_fast(float x) {
  return __builtin_amdgcn_rcpf(1.f + __expf(-x));
}
__device__ __forceinline__ float tanhf_fast(float x) {
  return 1.f - 2.f * __builtin_amdgcn_rcpf(__expf(2.f * x) + 1.f);
}

__global__ __launch_bounds__(512, 2) void gru_scan_kernel(
    const _Float16* __restrict__ WhT,   // [768][256]
    const _Float16* __restrict__ gi,    // [T][B][768] f16
    const int* __restrict__ resets,     // [T][B] int32
    const float* __restrict__ h0,       // [B][256]
    const float* __restrict__ bhn,      // [256]
    float* __restrict__ ys)             // [T][B][256]
{
  const int b    = blockIdx.x;
  const int s    = threadIdx.x;   // 0..511
  const int j    = s >> 1;        // output index 0..255
  const int half = s & 1;         // k-half: [half*128, half*128+128)

  __shared__ __align__(16) _Float16 hbuf[2][H_DIM];

  // ---- persistent weights: 3 x 64 dwords (f16x2) ----
  u32 wR[64], wZ[64], wN[64];
  {
    const uint4* pR = (const uint4*)(WhT + (size_t)j         * H_DIM + half * 128);
    const uint4* pZ = (const uint4*)(WhT + (size_t)(j + 256) * H_DIM + half * 128);
    const uint4* pN = (const uint4*)(WhT + (size_t)(j + 512) * H_DIM + half * 128);
#pragma unroll
    for (int i = 0; i < 16; ++i) {
      uint4 v = pR[i]; wR[4*i]=v.x; wR[4*i+1]=v.y; wR[4*i+2]=v.z; wR[4*i+3]=v.w;
    }
#pragma unroll
    for (int i = 0; i < 16; ++i) {
      uint4 v = pZ[i]; wZ[4*i]=v.x; wZ[4*i+1]=v.y; wZ[4*i+2]=v.z; wZ[4*i+3]=v.w;
    }
#pragma unroll
    for (int i = 0; i < 16; ++i) {
      uint4 v = pN[i]; wN[4*i]=v.x; wN[4*i+1]=v.y; wN[4*i+2]=v.z; wN[4*i+3]=v.w;
    }
  }

  const float bn = bhn[j];

  // ---- init carry (masked by resets[0]) ----
  float hprev;
  {
    const int r0 = resets[b];
    hprev = r0 ? 0.f : h0[(size_t)b * H_DIM + j];
    if (half == 0) hbuf[0][j] = (_Float16)hprev;
  }
  __syncthreads();

  const _Float16* gbase = gi + (size_t)b * G_DIM;
  float* ybase = ys + (size_t)b * H_DIM + j;

  int p = 0;
  for (int t = 0; t < T_DIM; ++t) {
    // issued early, consumed late (latency hidden under dot loop)
    const _Float16* gp = gbase + (size_t)t * (B_DIM * G_DIM);
    const float giR = (float)gp[j];
    const float giZ = (float)gp[j + 256];
    const float giN = (float)gp[j + 512];
    const int rstn = (t + 1 < T_DIM) ? resets[(t + 1) * B_DIM + b] : 0;

    float aR = 0.f, aZ = 0.f, aN = 0.f;
    const uint4* hb = (const uint4*)(&hbuf[p][half * 128]);
#pragma unroll
    for (int c = 0; c < 16; ++c) {
      const uint4 hv = hb[c];                     // broadcast ds_read_b128
      aR = dot2f(wR[4*c  ], hv.x, aR);
      aZ = dot2f(wZ[4*c  ], hv.x, aZ);
      aN = dot2f(wN[4*c  ], hv.x, aN);
      aR = dot2f(wR[4*c+1], hv.y, aR);
      aZ = dot2f(wZ[4*c+1], hv.y, aZ);
      aN = dot2f(wN[4*c+1], hv.y, aN);
      aR = dot2f(wR[4*c+2], hv.z, aR);
      aZ = dot2f(wZ[4*c+2], hv.z, aZ);
      aN = dot2f(wN[4*c+2], hv.z, aN);
      aR = dot2f(wR[4*c+3], hv.w, aR);
      aZ = dot2f(wZ[4*c+3], hv.w, aZ);
      aN = dot2f(wN[4*c+3], hv.w, aN);
    }

    // combine k-halves within the lane pair (both lanes end with full sums)
    aR += __shfl_xor(aR, 1);
    aZ += __shfl_xor(aZ, 1);
    aN += __shfl_xor(aN, 1);

    // activation, computed redundantly by both halves (no LDS exchange)
    const float r  = sigmoidf_fast(aR + giR);
    const float z  = sigmoidf_fast(aZ + giZ);
    const float n  = tanhf_fast(giN + r * (aN + bn));
    const float hn = (1.f - z) * n + z * hprev;

    // FIX: mask BEFORE storing the carry; ys still gets unmasked hn
    const float hnext = rstn ? 0.f : hn;
    if (half == 0) {
      hbuf[p ^ 1][j] = (_Float16)hnext;           // next step's broadcast copy
    } else {
      ybase[(size_t)t * (B_DIM * H_DIM)] = hn;    // output store
    }
    hprev = hnext;

    __syncthreads();                              // single barrier per step
    p ^= 1;
  }
}

// sentinel: distinctive failure signature if workspace is too small
__global__ void sentinel_kernel(float* out, int n) {
  int i = blockIdx.x * 256 + threadIdx.x;
  if (i < n) out[i] = 12345.0f;
}

// ---------------------------------------------------------------------------
extern "C" void kernel_launch(void* const* d_in, const int* in_sizes, int n_in,
                              void* d_out, int out_size, void* d_ws, size_t ws_size,
                              hipStream_t stream) {
  const float* ins    = (const float*)d_in[0];
  const int*   resets = (const int*)d_in[1];
  const float* h0     = (const float*)d_in[2];
  const float* Wi     = (const float*)d_in[3];
  const float* bi     = (const float*)d_in[4];
  const float* Wh     = (const float*)d_in[5];
  const float* bhn    = (const float*)d_in[6];
  float* ys = (float*)d_out;

  const size_t wbytes  = (size_t)G_DIM * H_DIM * 2;            // 393,216
  const size_t gibytes = (size_t)T_DIM * B_DIM * G_DIM * 2;    // 402,653,184
  const size_t need = 2 * wbytes + gibytes;
  if (ws_size < need) {
    sentinel_kernel<<<(out_size + 255) / 256, 256, 0, stream>>>(ys, out_size);
    return;
  }

  char* ws = (char*)d_ws;
  _Float16* WiT = (_Float16*)ws;
  _Float16* WhT = (_Float16*)(ws + wbytes);
  _Float16* gi  = (_Float16*)(ws + 2 * wbytes);

  prep_kernel<<<(2 * G_DIM * H_DIM) / 256, 256, 0, stream>>>(Wi, Wh, WiT, WhT);

  const int M = T_DIM * B_DIM;                 // 262144
  const int nblocks = (M / BM) * (G_DIM / BN); // 12288
  gemm_gi_kernel<<<nblocks, 256, 0, stream>>>(ins, WiT, bi, gi);

  gru_scan_kernel<<<B_DIM, 512, 0, stream>>>(WhT, gi, resets, h0, bhn, ys);
}